// Round 1
// baseline (689.288 us; speedup 1.0000x reference)
//
#include <hip/hip_runtime.h>

// SelfAttention: B=4 S=2048 D=1024 H=16 HD=64, causal, fp32 in/out, bf16 MFMA compute.
// R0: correctness-first full pipeline. GEMMs: 128x128 block tile, 64x64/wave,
// direct global->fragment loads (no LDS yet). Attention: flash-style, S^T=K.Q^T
// trick so P lands in A-operand layout for PV (no LDS transpose).

typedef __attribute__((ext_vector_type(8))) short short8_t;
typedef __attribute__((ext_vector_type(4))) short short4_t;
typedef __attribute__((ext_vector_type(4))) float float4_t;

constexpr int Bz = 4, Sq = 2048, Dm = 1024, NH = 16, HD = 64;

__device__ __forceinline__ unsigned short f2bf(float f) {
  unsigned u = __builtin_bit_cast(unsigned, f);
  u += 0x7fffu + ((u >> 16) & 1u);
  return (unsigned short)(u >> 16);
}

__global__ __launch_bounds__(256) void cast_x_kernel(const float* __restrict__ x,
                                                     unsigned short* __restrict__ xb) {
  size_t i = (size_t)blockIdx.x * 256 + threadIdx.x;  // grid sized exactly: N/4 threads
  float4 v = ((const float4*)x)[i];
  ushort4 o;
  o.x = f2bf(v.x); o.y = f2bf(v.y); o.z = f2bf(v.z); o.w = f2bf(v.w);
  ((ushort4*)xb)[i] = o;
}

// W [K=1024][N=1024] fp32 -> WT [N][K] bf16 (so GEMM B-fragments are contiguous)
__global__ __launch_bounds__(256) void transpose_w_kernel(const float* __restrict__ W,
                                                          unsigned short* __restrict__ WT) {
  __shared__ float tile[64][65];
  int n0 = blockIdx.x * 64, k0 = blockIdx.y * 64;
  int tx = threadIdx.x & 63, ty = threadIdx.x >> 6;
#pragma unroll
  for (int i = 0; i < 16; ++i) {
    int r = i * 4 + ty;
    tile[r][tx] = W[(size_t)(k0 + r) * Dm + n0 + tx];
  }
  __syncthreads();
#pragma unroll
  for (int i = 0; i < 16; ++i) {
    int r = i * 4 + ty;
    WT[(size_t)(n0 + r) * Dm + k0 + tx] = f2bf(tile[tx][r]);
  }
}

// Core: C[64x64 per wave] = A[m,k] * B[k,n], A row-major [M,1024] bf16,
// BT row-major [N,1024] bf16 (i.e. B transposed). K=1024 fixed.
__device__ __forceinline__ void gemm_core(const unsigned short* __restrict__ A,
                                          const unsigned short* __restrict__ BT,
                                          int m_base, int n_base, int lr, int quad,
                                          float4_t acc[4][4]) {
  const unsigned short* ap = A + (size_t)(m_base + lr) * Dm + quad * 8;
  const unsigned short* bp = BT + (size_t)(n_base + lr) * Dm + quad * 8;
#pragma unroll 2
  for (int kk = 0; kk < 32; ++kk) {
    short8_t a[4], b[4];
#pragma unroll
    for (int i = 0; i < 4; ++i)
      a[i] = *(const short8_t*)(ap + (size_t)i * 16 * Dm + kk * 32);
#pragma unroll
    for (int j = 0; j < 4; ++j)
      b[j] = *(const short8_t*)(bp + (size_t)j * 16 * Dm + kk * 32);
#pragma unroll
    for (int i = 0; i < 4; ++i)
#pragma unroll
      for (int j = 0; j < 4; ++j)
        acc[i][j] = __builtin_amdgcn_mfma_f32_16x16x32_bf16(a[i], b[j], acc[i][j], 0, 0, 0);
  }
}

// QKV projections: x_bf16 [8192,1024] @ W -> [B,H,S,HD] bf16. grid (64,8,3)
__global__ __launch_bounds__(256) void gemm_qkv_kernel(
    const unsigned short* __restrict__ xb,
    const unsigned short* __restrict__ wqT, const unsigned short* __restrict__ wkT,
    const unsigned short* __restrict__ wvT,
    unsigned short* __restrict__ qb, unsigned short* __restrict__ kb,
    unsigned short* __restrict__ vb) {
  const unsigned short* WT = blockIdx.z == 0 ? wqT : (blockIdx.z == 1 ? wkT : wvT);
  unsigned short* outb = blockIdx.z == 0 ? qb : (blockIdx.z == 1 ? kb : vb);
  int wave = threadIdx.x >> 6, lane = threadIdx.x & 63;
  int lr = lane & 15, quad = lane >> 4;
  int m_base = blockIdx.x * 128 + (wave >> 1) * 64;
  int n_base = blockIdx.y * 128 + (wave & 1) * 64;
  float4_t z = {0.f, 0.f, 0.f, 0.f};
  float4_t acc[4][4];
#pragma unroll
  for (int i = 0; i < 4; ++i)
#pragma unroll
    for (int j = 0; j < 4; ++j) acc[i][j] = z;
  gemm_core(xb, WT, m_base, n_base, lr, quad, acc);
#pragma unroll
  for (int i = 0; i < 4; ++i)
#pragma unroll
    for (int j = 0; j < 4; ++j)
#pragma unroll
      for (int r = 0; r < 4; ++r) {
        int m = m_base + i * 16 + quad * 4 + r;  // C/D: row=quad*4+reg
        int n = n_base + j * 16 + lr;            //       col=lane&15
        int b = m >> 11, s = m & (Sq - 1);
        int h = n >> 6, hd = n & (HD - 1);
        outb[(((size_t)b * NH + h) * Sq + s) * HD + hd] = f2bf(acc[i][j][r]);
      }
}

// Output projection: ao_bf16 [8192,1024] @ Wo -> fp32 d_out. grid (64,8)
__global__ __launch_bounds__(256) void gemm_out_kernel(
    const unsigned short* __restrict__ ao, const unsigned short* __restrict__ woT,
    float* __restrict__ out) {
  int wave = threadIdx.x >> 6, lane = threadIdx.x & 63;
  int lr = lane & 15, quad = lane >> 4;
  int m_base = blockIdx.x * 128 + (wave >> 1) * 64;
  int n_base = blockIdx.y * 128 + (wave & 1) * 64;
  float4_t z = {0.f, 0.f, 0.f, 0.f};
  float4_t acc[4][4];
#pragma unroll
  for (int i = 0; i < 4; ++i)
#pragma unroll
    for (int j = 0; j < 4; ++j) acc[i][j] = z;
  gemm_core(ao, woT, m_base, n_base, lr, quad, acc);
#pragma unroll
  for (int i = 0; i < 4; ++i)
#pragma unroll
    for (int j = 0; j < 4; ++j)
#pragma unroll
      for (int r = 0; r < 4; ++r) {
        int m = m_base + i * 16 + quad * 4 + r;
        int n = n_base + j * 16 + lr;
        out[(size_t)m * Dm + n] = acc[i][j][r];
      }
}

// Flash attention: one wave = 16 query rows of one (b,h). grid (S/64, B*H), block 256.
// Computes S^T = K.Q^T so scores land as ST[key=quad*4+reg][q=lane&15]:
//  - softmax stats per q => shfl_xor 16/32 reductions
//  - P is then ALREADY in mfma_16x16x16 A-layout (A[m=q=lane&15][k=key=quad*4+j])
__global__ __launch_bounds__(256) void attn_kernel(
    const unsigned short* __restrict__ qbuf, const unsigned short* __restrict__ kbuf,
    const unsigned short* __restrict__ vbuf, unsigned short* __restrict__ ao) {
  int bh = blockIdx.y;
  int wave = threadIdx.x >> 6, lane = threadIdx.x & 63;
  int lcol = lane & 15, quad = lane >> 4;
  int q0 = blockIdx.x * 64 + wave * 16;
  const unsigned short* Q = qbuf + (size_t)bh * Sq * HD;
  const unsigned short* K = kbuf + (size_t)bh * Sq * HD;
  const unsigned short* V = vbuf + (size_t)bh * Sq * HD;

  // Q fragments (B-operand of S^T mfma): B[k=hd][n=q] -> contiguous hd from Q row
  short8_t qf0 = *(const short8_t*)(Q + (size_t)(q0 + lcol) * HD + quad * 8);
  short8_t qf1 = *(const short8_t*)(Q + (size_t)(q0 + lcol) * HD + 32 + quad * 8);

  float m_i = -INFINITY, l_i = 0.f;
  float4_t z = {0.f, 0.f, 0.f, 0.f};
  float4_t o[4];
#pragma unroll
  for (int f = 0; f < 4; ++f) o[f] = z;

  int q_global = q0 + lcol;
  int ktiles = q0 / 16 + 1;  // causal: key tiles 0..q0/16
  for (int kt = 0; kt < ktiles; ++kt) {
    int key0 = kt * 16;
    short8_t kf0 = *(const short8_t*)(K + (size_t)(key0 + lcol) * HD + quad * 8);
    short8_t kf1 = *(const short8_t*)(K + (size_t)(key0 + lcol) * HD + 32 + quad * 8);
    float4_t st = z;
    st = __builtin_amdgcn_mfma_f32_16x16x32_bf16(kf0, qf0, st, 0, 0, 0);
    st = __builtin_amdgcn_mfma_f32_16x16x32_bf16(kf1, qf1, st, 0, 0, 0);

    float s[4];
    float tmax = -INFINITY;
#pragma unroll
    for (int r = 0; r < 4; ++r) {
      int key = key0 + quad * 4 + r;
      float v = st[r] * 0.125f;               // 1/sqrt(64)
      if (key > q_global) v = -INFINITY;      // causal mask
      s[r] = v;
      tmax = fmaxf(tmax, v);
    }
    tmax = fmaxf(tmax, __shfl_xor(tmax, 16, 64));
    tmax = fmaxf(tmax, __shfl_xor(tmax, 32, 64));
    float m_new = fmaxf(m_i, tmax);
    float alpha = __expf(m_i - m_new);  // m_i=-inf first iter -> 0
    float psum = 0.f;
    short4_t pf;
#pragma unroll
    for (int r = 0; r < 4; ++r) {
      float p = __expf(s[r] - m_new);  // masked -> exp(-inf)=0
      psum += p;
      pf[r] = (short)f2bf(p);
    }
    psum += __shfl_xor(psum, 16, 64);
    psum += __shfl_xor(psum, 32, 64);
    l_i = l_i * alpha + psum;
    m_i = m_new;

    // transpose alpha to O's row layout (row q = quad*4+r)
    float at[4];
#pragma unroll
    for (int r = 0; r < 4; ++r) at[r] = __shfl(alpha, quad * 4 + r, 64);
#pragma unroll
    for (int f = 0; f < 4; ++f)
#pragma unroll
      for (int r = 0; r < 4; ++r) o[f][r] *= at[r];

#pragma unroll
    for (int f = 0; f < 4; ++f) {
      short4_t vf;  // B[k=key=quad*4+j][n=hd=f*16+lcol]
#pragma unroll
      for (int j = 0; j < 4; ++j)
        vf[j] = (short)V[(size_t)(key0 + quad * 4 + j) * HD + f * 16 + lcol];
      o[f] = __builtin_amdgcn_mfma_f32_16x16x16bf16_1k(pf, vf, o[f], 0, 0, 0);
    }
  }

  float lt[4];
#pragma unroll
  for (int r = 0; r < 4; ++r) lt[r] = 1.f / __shfl(l_i, quad * 4 + r, 64);
  int b = bh >> 4, h = bh & 15;
#pragma unroll
  for (int f = 0; f < 4; ++f)
#pragma unroll
    for (int r = 0; r < 4; ++r) {
      int q = q0 + quad * 4 + r;
      int hd = f * 16 + lcol;
      ao[((size_t)b * Sq + q) * (NH * HD) + h * HD + hd] = f2bf(o[f][r] * lt[r]);
    }
}

extern "C" void kernel_launch(void* const* d_in, const int* in_sizes, int n_in,
                              void* d_out, int out_size, void* d_ws, size_t ws_size,
                              hipStream_t stream) {
  const float* x = (const float*)d_in[0];
  const float* Wq = (const float*)d_in[1];
  const float* Wk = (const float*)d_in[2];
  const float* Wv = (const float*)d_in[3];
  const float* Wo = (const float*)d_in[4];
  float* out = (float*)d_out;

  char* ws = (char*)d_ws;
  size_t off = 0;
  auto carve = [&](size_t bytes) {
    void* p = ws + off;
    off += (bytes + 255) & ~(size_t)255;
    return p;
  };
  const size_t xe = (size_t)Bz * Sq * Dm;        // 8.4M elems
  const size_t we = (size_t)Dm * Dm;             // 1M elems
  unsigned short* xb = (unsigned short*)carve(xe * 2);
  unsigned short* wqT = (unsigned short*)carve(we * 2);
  unsigned short* wkT = (unsigned short*)carve(we * 2);
  unsigned short* wvT = (unsigned short*)carve(we * 2);
  unsigned short* woT = (unsigned short*)carve(we * 2);
  unsigned short* qb = (unsigned short*)carve(xe * 2);
  unsigned short* kb = (unsigned short*)carve(xe * 2);
  unsigned short* vb = (unsigned short*)carve(xe * 2);
  unsigned short* ao = (unsigned short*)carve(xe * 2);
  (void)ws_size;

  cast_x_kernel<<<xe / 4 / 256, 256, 0, stream>>>(x, xb);
  transpose_w_kernel<<<dim3(16, 16), 256, 0, stream>>>(Wq, wqT);
  transpose_w_kernel<<<dim3(16, 16), 256, 0, stream>>>(Wk, wkT);
  transpose_w_kernel<<<dim3(16, 16), 256, 0, stream>>>(Wv, wvT);
  transpose_w_kernel<<<dim3(16, 16), 256, 0, stream>>>(Wo, woT);
  gemm_qkv_kernel<<<dim3(64, 8, 3), 256, 0, stream>>>(xb, wqT, wkT, wvT, qb, kb, vb);
  attn_kernel<<<dim3(Sq / 64, Bz * NH), 256, 0, stream>>>(qb, kb, vb, ao);
  gemm_out_kernel<<<dim3(64, 8), 256, 0, stream>>>(ao, woT, out);
}

// Round 3
// 427.796 us; speedup vs baseline: 1.6113x; 1.6113x over previous
//
#include <hip/hip_runtime.h>

// SelfAttention: B=4 S=2048 D=1024 H=16 HD=64, causal, fp32 in/out, bf16 MFMA compute.
// R2: fix R1's staging bug (each thread must write 16 elems/buffer, not 8 —
// half of lk/lv was uninitialized -> NaN). Design otherwise identical to R1:
// work-paired blocks {t, 31-t}, 64-key K-steps, LDS-staged K + pre-transposed V.

typedef __attribute__((ext_vector_type(8))) short short8_t;
typedef __attribute__((ext_vector_type(4))) short short4_t;
typedef __attribute__((ext_vector_type(4))) float float4_t;

constexpr int Bz = 4, Sq = 2048, Dm = 1024, NH = 16, HD = 64;
constexpr int LDSPITCH = 72;  // 64 + 8 elems

__device__ __forceinline__ unsigned short f2bf(float f) {
  unsigned u = __builtin_bit_cast(unsigned, f);
  u += 0x7fffu + ((u >> 16) & 1u);
  return (unsigned short)(u >> 16);
}

__global__ __launch_bounds__(256) void cast_x_kernel(const float* __restrict__ x,
                                                     unsigned short* __restrict__ xb) {
  size_t i = (size_t)blockIdx.x * 256 + threadIdx.x;
  float4 v = ((const float4*)x)[i];
  ushort4 o;
  o.x = f2bf(v.x); o.y = f2bf(v.y); o.z = f2bf(v.z); o.w = f2bf(v.w);
  ((ushort4*)xb)[i] = o;
}

// W [K=1024][N=1024] fp32 -> WT [N][K] bf16
__global__ __launch_bounds__(256) void transpose_w_kernel(const float* __restrict__ W,
                                                          unsigned short* __restrict__ WT) {
  __shared__ float tile[64][65];
  int n0 = blockIdx.x * 64, k0 = blockIdx.y * 64;
  int tx = threadIdx.x & 63, ty = threadIdx.x >> 6;
#pragma unroll
  for (int i = 0; i < 16; ++i) {
    int r = i * 4 + ty;
    tile[r][tx] = W[(size_t)(k0 + r) * Dm + n0 + tx];
  }
  __syncthreads();
#pragma unroll
  for (int i = 0; i < 16; ++i) {
    int r = i * 4 + ty;
    WT[(size_t)(n0 + r) * Dm + k0 + tx] = f2bf(tile[tx][r]);
  }
}

__device__ __forceinline__ void gemm_core(const unsigned short* __restrict__ A,
                                          const unsigned short* __restrict__ BT,
                                          int m_base, int n_base, int lr, int quad,
                                          float4_t acc[4][4]) {
  const unsigned short* ap = A + (size_t)(m_base + lr) * Dm + quad * 8;
  const unsigned short* bp = BT + (size_t)(n_base + lr) * Dm + quad * 8;
#pragma unroll 2
  for (int kk = 0; kk < 32; ++kk) {
    short8_t a[4], b[4];
#pragma unroll
    for (int i = 0; i < 4; ++i)
      a[i] = *(const short8_t*)(ap + (size_t)i * 16 * Dm + kk * 32);
#pragma unroll
    for (int j = 0; j < 4; ++j)
      b[j] = *(const short8_t*)(bp + (size_t)j * 16 * Dm + kk * 32);
#pragma unroll
    for (int i = 0; i < 4; ++i)
#pragma unroll
      for (int j = 0; j < 4; ++j)
        acc[i][j] = __builtin_amdgcn_mfma_f32_16x16x32_bf16(a[i], b[j], acc[i][j], 0, 0, 0);
  }
}

// QKV projections. Q,K -> [B,H,S,HD]; V -> TRANSPOSED [B,H,HD,S]. grid (64,8,3)
__global__ __launch_bounds__(256) void gemm_qkv_kernel(
    const unsigned short* __restrict__ xb,
    const unsigned short* __restrict__ wqT, const unsigned short* __restrict__ wkT,
    const unsigned short* __restrict__ wvT,
    unsigned short* __restrict__ qb, unsigned short* __restrict__ kb,
    unsigned short* __restrict__ vt) {
  const unsigned short* WT = blockIdx.z == 0 ? wqT : (blockIdx.z == 1 ? wkT : wvT);
  unsigned short* outb = blockIdx.z == 0 ? qb : (blockIdx.z == 1 ? kb : vt);
  bool isV = blockIdx.z == 2;
  int wave = threadIdx.x >> 6, lane = threadIdx.x & 63;
  int lr = lane & 15, quad = lane >> 4;
  int m_base = blockIdx.x * 128 + (wave >> 1) * 64;
  int n_base = blockIdx.y * 128 + (wave & 1) * 64;
  float4_t z = {0.f, 0.f, 0.f, 0.f};
  float4_t acc[4][4];
#pragma unroll
  for (int i = 0; i < 4; ++i)
#pragma unroll
    for (int j = 0; j < 4; ++j) acc[i][j] = z;
  gemm_core(xb, WT, m_base, n_base, lr, quad, acc);
  if (isV) {
#pragma unroll
    for (int i = 0; i < 4; ++i)
#pragma unroll
      for (int j = 0; j < 4; ++j) {
        int m = m_base + i * 16 + quad * 4;  // +r consecutive tokens
        int n = n_base + j * 16 + lr;
        int b = m >> 11, s = m & (Sq - 1);
        int h = n >> 6, hd = n & (HD - 1);
        ushort4 pk;
        pk.x = f2bf(acc[i][j][0]); pk.y = f2bf(acc[i][j][1]);
        pk.z = f2bf(acc[i][j][2]); pk.w = f2bf(acc[i][j][3]);
        *(ushort4*)(outb + (((size_t)b * NH + h) * HD + hd) * Sq + s) = pk;
      }
  } else {
#pragma unroll
    for (int i = 0; i < 4; ++i)
#pragma unroll
      for (int j = 0; j < 4; ++j)
#pragma unroll
        for (int r = 0; r < 4; ++r) {
          int m = m_base + i * 16 + quad * 4 + r;
          int n = n_base + j * 16 + lr;
          int b = m >> 11, s = m & (Sq - 1);
          int h = n >> 6, hd = n & (HD - 1);
          outb[(((size_t)b * NH + h) * Sq + s) * HD + hd] = f2bf(acc[i][j][r]);
        }
  }
}

// Output projection: ao_bf16 [8192,1024] @ Wo -> fp32 out. grid (64,8)
__global__ __launch_bounds__(256) void gemm_out_kernel(
    const unsigned short* __restrict__ ao, const unsigned short* __restrict__ woT,
    float* __restrict__ out) {
  int wave = threadIdx.x >> 6, lane = threadIdx.x & 63;
  int lr = lane & 15, quad = lane >> 4;
  int m_base = blockIdx.x * 128 + (wave >> 1) * 64;
  int n_base = blockIdx.y * 128 + (wave & 1) * 64;
  float4_t z = {0.f, 0.f, 0.f, 0.f};
  float4_t acc[4][4];
#pragma unroll
  for (int i = 0; i < 4; ++i)
#pragma unroll
    for (int j = 0; j < 4; ++j) acc[i][j] = z;
  gemm_core(ao, woT, m_base, n_base, lr, quad, acc);
#pragma unroll
  for (int i = 0; i < 4; ++i)
#pragma unroll
    for (int j = 0; j < 4; ++j)
#pragma unroll
      for (int r = 0; r < 4; ++r) {
        int m = m_base + i * 16 + quad * 4 + r;
        int n = n_base + j * 16 + lr;
        out[(size_t)m * Dm + n] = acc[i][j][r];
      }
}

// Flash attention v2. grid (16, B*H), block 256 (4 waves).
// Block processes q-tiles {t, 31-t} (64 rows each) => every block = 33 key-tiles.
__global__ __launch_bounds__(256) void attn_kernel(
    const unsigned short* __restrict__ qbuf, const unsigned short* __restrict__ kbuf,
    const unsigned short* __restrict__ vtbuf, unsigned short* __restrict__ ao) {
  __shared__ unsigned short lk[64 * LDSPITCH];
  __shared__ unsigned short lv[64 * LDSPITCH];
  int bh = blockIdx.y;
  int wave = threadIdx.x >> 6, lane = threadIdx.x & 63;
  int lcol = lane & 15, quad = lane >> 4;
  const unsigned short* Q = qbuf + (size_t)bh * Sq * HD;
  const unsigned short* K = kbuf + (size_t)bh * Sq * HD;
  const unsigned short* Vt = vtbuf + (size_t)bh * HD * Sq;
  int b = bh >> 4, h = bh & 15;
  int srow = threadIdx.x >> 2;        // staging row 0..63
  int scol = (threadIdx.x & 3) * 16;  // staging col: 16 elems per thread per buffer
  float4_t z = {0.f, 0.f, 0.f, 0.f};

  for (int half = 0; half < 2; ++half) {
    int ti = half == 0 ? (int)blockIdx.x : 31 - (int)blockIdx.x;
    int q0w = ti * 64 + wave * 16;
    int q_global = q0w + lcol;
    short8_t qf0 = *(const short8_t*)(Q + (size_t)(q0w + lcol) * HD + quad * 8);
    short8_t qf1 = *(const short8_t*)(Q + (size_t)(q0w + lcol) * HD + 32 + quad * 8);
    float m_i = -INFINITY, l_i = 0.f;
    float4_t o[4];
#pragma unroll
    for (int f = 0; f < 4; ++f) o[f] = z;

    int nkt = ti + 1;
    for (int kt = 0; kt < nkt; ++kt) {
      int key0 = kt * 64;
      __syncthreads();
      {
        const unsigned short* kg = K + (size_t)(key0 + srow) * HD + scol;
        const unsigned short* vg = Vt + (size_t)srow * Sq + key0 + scol;
        unsigned short* kl = lk + srow * LDSPITCH + scol;
        unsigned short* vl = lv + srow * LDSPITCH + scol;
        *(short8_t*)(kl) = *(const short8_t*)(kg);
        *(short8_t*)(kl + 8) = *(const short8_t*)(kg + 8);
        *(short8_t*)(vl) = *(const short8_t*)(vg);
        *(short8_t*)(vl + 8) = *(const short8_t*)(vg + 8);
      }
      __syncthreads();

      bool need_mask = (key0 + 63 > q0w);
      float s[16];
      float tmax = -INFINITY;
#pragma unroll
      for (int s4 = 0; s4 < 4; ++s4) {
        short8_t kf0 = *(const short8_t*)(lk + (s4 * 16 + lcol) * LDSPITCH + quad * 8);
        short8_t kf1 = *(const short8_t*)(lk + (s4 * 16 + lcol) * LDSPITCH + 32 + quad * 8);
        float4_t st = z;
        st = __builtin_amdgcn_mfma_f32_16x16x32_bf16(kf0, qf0, st, 0, 0, 0);
        st = __builtin_amdgcn_mfma_f32_16x16x32_bf16(kf1, qf1, st, 0, 0, 0);
#pragma unroll
        for (int r = 0; r < 4; ++r) {
          float v = st[r] * 0.125f;  // 1/sqrt(64)
          if (need_mask && (key0 + s4 * 16 + quad * 4 + r > q_global)) v = -INFINITY;
          s[s4 * 4 + r] = v;
          tmax = fmaxf(tmax, v);
        }
      }
      tmax = fmaxf(tmax, __shfl_xor(tmax, 16, 64));
      tmax = fmaxf(tmax, __shfl_xor(tmax, 32, 64));
      float m_new = fmaxf(m_i, tmax);
      float alpha = __expf(m_i - m_new);  // first tile: exp(-inf)=0
      float psum = 0.f;
      short4_t pf[4];
#pragma unroll
      for (int s4 = 0; s4 < 4; ++s4)
#pragma unroll
        for (int r = 0; r < 4; ++r) {
          float p = __expf(s[s4 * 4 + r] - m_new);
          psum += p;
          pf[s4][r] = (short)f2bf(p);
        }
      psum += __shfl_xor(psum, 16, 64);
      psum += __shfl_xor(psum, 32, 64);
      l_i = l_i * alpha + psum;
      m_i = m_new;
      float at[4];
#pragma unroll
      for (int r = 0; r < 4; ++r) at[r] = __shfl(alpha, quad * 4 + r, 64);
#pragma unroll
      for (int f = 0; f < 4; ++f)
#pragma unroll
        for (int r = 0; r < 4; ++r) o[f][r] *= at[r];
#pragma unroll
      for (int f = 0; f < 4; ++f)
#pragma unroll
        for (int s4 = 0; s4 < 4; ++s4) {
          short4_t vf =
              *(const short4_t*)(lv + (f * 16 + lcol) * LDSPITCH + s4 * 16 + quad * 4);
          o[f] = __builtin_amdgcn_mfma_f32_16x16x16bf16_1k(pf[s4], vf, o[f], 0, 0, 0);
        }
    }

    float lt[4];
#pragma unroll
    for (int r = 0; r < 4; ++r) lt[r] = 1.f / __shfl(l_i, quad * 4 + r, 64);
#pragma unroll
    for (int f = 0; f < 4; ++f)
#pragma unroll
      for (int r = 0; r < 4; ++r) {
        int q = q0w + quad * 4 + r;
        int hd = f * 16 + lcol;
        ao[((size_t)b * Sq + q) * (NH * HD) + h * HD + hd] = f2bf(o[f][r] * lt[r]);
      }
  }
}

extern "C" void kernel_launch(void* const* d_in, const int* in_sizes, int n_in,
                              void* d_out, int out_size, void* d_ws, size_t ws_size,
                              hipStream_t stream) {
  const float* x = (const float*)d_in[0];
  const float* Wq = (const float*)d_in[1];
  const float* Wk = (const float*)d_in[2];
  const float* Wv = (const float*)d_in[3];
  const float* Wo = (const float*)d_in[4];
  float* out = (float*)d_out;

  char* ws = (char*)d_ws;
  size_t off = 0;
  auto carve = [&](size_t bytes) {
    void* p = ws + off;
    off += (bytes + 255) & ~(size_t)255;
    return p;
  };
  const size_t xe = (size_t)Bz * Sq * Dm;
  const size_t we = (size_t)Dm * Dm;
  unsigned short* xb = (unsigned short*)carve(xe * 2);
  unsigned short* wqT = (unsigned short*)carve(we * 2);
  unsigned short* wkT = (unsigned short*)carve(we * 2);
  unsigned short* wvT = (unsigned short*)carve(we * 2);
  unsigned short* woT = (unsigned short*)carve(we * 2);
  unsigned short* qb = (unsigned short*)carve(xe * 2);
  unsigned short* kb = (unsigned short*)carve(xe * 2);
  unsigned short* vt = (unsigned short*)carve(xe * 2);
  unsigned short* ao = (unsigned short*)carve(xe * 2);
  (void)ws_size;

  cast_x_kernel<<<xe / 4 / 256, 256, 0, stream>>>(x, xb);
  transpose_w_kernel<<<dim3(16, 16), 256, 0, stream>>>(Wq, wqT);
  transpose_w_kernel<<<dim3(16, 16), 256, 0, stream>>>(Wk, wkT);
  transpose_w_kernel<<<dim3(16, 16), 256, 0, stream>>>(Wv, wvT);
  transpose_w_kernel<<<dim3(16, 16), 256, 0, stream>>>(Wo, woT);
  gemm_qkv_kernel<<<dim3(64, 8, 3), 256, 0, stream>>>(xb, wqT, wkT, wvT, qb, kb, vt);
  attn_kernel<<<dim3(16, Bz * NH), 256, 0, stream>>>(qb, kb, vt, ao);
  gemm_out_kernel<<<dim3(64, 8), 256, 0, stream>>>(ao, woT, out);
}

// Round 4
// 301.555 us; speedup vs baseline: 2.2858x; 1.4186x over previous
//
#include <hip/hip_runtime.h>

// SelfAttention: B=4 S=2048 D=1024 H=16 HD=64, causal, fp32 in/out, bf16 MFMA compute.
// R3: GEMMs rewritten to m97-style LDS-staged main loop: 128x128 tile, BK=64,
// global_load_lds width=16 staging (unpadded [128][64] LDS, lane-contiguous),
// ds_read_b128 fragments, 32 MFMA per barrier pair. Attention unchanged from R2.

typedef __attribute__((ext_vector_type(8))) short short8_t;
typedef __attribute__((ext_vector_type(4))) short short4_t;
typedef __attribute__((ext_vector_type(4))) float float4_t;

constexpr int Bz = 4, Sq = 2048, Dm = 1024, NH = 16, HD = 64;
constexpr int LDSPITCH = 72;  // attn LDS pitch

#define GLOAD_LDS16(g, l)                                                      \
  __builtin_amdgcn_global_load_lds(                                            \
      (const __attribute__((address_space(1))) unsigned int*)(g),              \
      (__attribute__((address_space(3))) unsigned int*)(l), 16, 0, 0)

__device__ __forceinline__ unsigned short f2bf(float f) {
  unsigned u = __builtin_bit_cast(unsigned, f);
  u += 0x7fffu + ((u >> 16) & 1u);
  return (unsigned short)(u >> 16);
}

__global__ __launch_bounds__(256) void cast_x_kernel(const float* __restrict__ x,
                                                     unsigned short* __restrict__ xb) {
  size_t i = (size_t)blockIdx.x * 256 + threadIdx.x;
  float4 v = ((const float4*)x)[i];
  ushort4 o;
  o.x = f2bf(v.x); o.y = f2bf(v.y); o.z = f2bf(v.z); o.w = f2bf(v.w);
  ((ushort4*)xb)[i] = o;
}

// W [K=1024][N=1024] fp32 -> WT [N][K] bf16
__global__ __launch_bounds__(256) void transpose_w_kernel(const float* __restrict__ W,
                                                          unsigned short* __restrict__ WT) {
  __shared__ float tile[64][65];
  int n0 = blockIdx.x * 64, k0 = blockIdx.y * 64;
  int tx = threadIdx.x & 63, ty = threadIdx.x >> 6;
#pragma unroll
  for (int i = 0; i < 16; ++i) {
    int r = i * 4 + ty;
    tile[r][tx] = W[(size_t)(k0 + r) * Dm + n0 + tx];
  }
  __syncthreads();
#pragma unroll
  for (int i = 0; i < 16; ++i) {
    int r = i * 4 + ty;
    WT[(size_t)(n0 + r) * Dm + k0 + tx] = f2bf(tile[tx][r]);
  }
}

// m97-style main loop: C_tile[128x128] += A[128xK] * BT[128xK]^T, K=1024.
// LDS tiles [128][64] bf16, unpadded (global_load_lds lane-contiguity).
// Each wave owns a 64x64 quadrant, acc[4][4] of 16x16 tiles.
__device__ __forceinline__ void gemm_mainloop(const unsigned short* __restrict__ A,
                                              const unsigned short* __restrict__ BT,
                                              int m0, int n0,
                                              unsigned short* lA, unsigned short* lB,
                                              float4_t acc[4][4]) {
  const int tid = threadIdx.x;
  const int lane = tid & 63, lr = lane & 15, quad = lane >> 4;
  const int wave = tid >> 6;
  const int mw = (wave >> 1) * 64, nw = (wave & 1) * 64;
  const int srow = tid >> 3;        // 0..31
  const int scol = (tid & 7) * 8;   // elems
  const unsigned short* ga = A + (size_t)(m0 + srow) * Dm + scol;
  const unsigned short* gb = BT + (size_t)(n0 + srow) * Dm + scol;
  unsigned short* la = lA + tid * 8;  // byte off = tid*16 = wave-uniform + lane*16
  unsigned short* lb = lB + tid * 8;

  for (int k0 = 0; k0 < Dm; k0 += 64) {
    __syncthreads();
#pragma unroll
    for (int iss = 0; iss < 4; ++iss) {
      GLOAD_LDS16(ga + (size_t)iss * 32 * Dm + k0, la + iss * 32 * 64);
      GLOAD_LDS16(gb + (size_t)iss * 32 * Dm + k0, lb + iss * 32 * 64);
    }
    __syncthreads();
#pragma unroll
    for (int kk = 0; kk < 2; ++kk) {
      short8_t a[4], b[4];
#pragma unroll
      for (int i = 0; i < 4; ++i)
        a[i] = *(const short8_t*)(lA + (mw + i * 16 + lr) * 64 + kk * 32 + quad * 8);
#pragma unroll
      for (int j = 0; j < 4; ++j)
        b[j] = *(const short8_t*)(lB + (nw + j * 16 + lr) * 64 + kk * 32 + quad * 8);
#pragma unroll
      for (int i = 0; i < 4; ++i)
#pragma unroll
        for (int j = 0; j < 4; ++j)
          acc[i][j] = __builtin_amdgcn_mfma_f32_16x16x32_bf16(a[i], b[j], acc[i][j], 0, 0, 0);
    }
  }
}

// QKV projections. Q,K -> [B,H,S,HD]; V -> TRANSPOSED [B,H,HD,S]. grid (8,64,3)
__global__ __launch_bounds__(256) void gemm_qkv_kernel(
    const unsigned short* __restrict__ xb,
    const unsigned short* __restrict__ wqT, const unsigned short* __restrict__ wkT,
    const unsigned short* __restrict__ wvT,
    unsigned short* __restrict__ qb, unsigned short* __restrict__ kb,
    unsigned short* __restrict__ vt) {
  __shared__ unsigned short lA[128 * 64];
  __shared__ unsigned short lB[128 * 64];
  const unsigned short* WT = blockIdx.z == 0 ? wqT : (blockIdx.z == 1 ? wkT : wvT);
  unsigned short* outb = blockIdx.z == 0 ? qb : (blockIdx.z == 1 ? kb : vt);
  bool isV = blockIdx.z == 2;
  int lane = threadIdx.x & 63, wave = threadIdx.x >> 6;
  int lr = lane & 15, quad = lane >> 4;
  int m0 = blockIdx.y * 128, n0 = blockIdx.x * 128;
  int m_base = m0 + (wave >> 1) * 64;
  int n_base = n0 + (wave & 1) * 64;
  float4_t z = {0.f, 0.f, 0.f, 0.f};
  float4_t acc[4][4];
#pragma unroll
  for (int i = 0; i < 4; ++i)
#pragma unroll
    for (int j = 0; j < 4; ++j) acc[i][j] = z;
  gemm_mainloop(xb, WT, m0, n0, lA, lB, acc);
  if (isV) {
#pragma unroll
    for (int i = 0; i < 4; ++i)
#pragma unroll
      for (int j = 0; j < 4; ++j) {
        int m = m_base + i * 16 + quad * 4;  // +r consecutive tokens
        int n = n_base + j * 16 + lr;
        int b = m >> 11, s = m & (Sq - 1);
        int h = n >> 6, hd = n & (HD - 1);
        ushort4 pk;
        pk.x = f2bf(acc[i][j][0]); pk.y = f2bf(acc[i][j][1]);
        pk.z = f2bf(acc[i][j][2]); pk.w = f2bf(acc[i][j][3]);
        *(ushort4*)(outb + (((size_t)b * NH + h) * HD + hd) * Sq + s) = pk;
      }
  } else {
#pragma unroll
    for (int i = 0; i < 4; ++i)
#pragma unroll
      for (int j = 0; j < 4; ++j)
#pragma unroll
        for (int r = 0; r < 4; ++r) {
          int m = m_base + i * 16 + quad * 4 + r;
          int n = n_base + j * 16 + lr;
          int b = m >> 11, s = m & (Sq - 1);
          int h = n >> 6, hd = n & (HD - 1);
          outb[(((size_t)b * NH + h) * Sq + s) * HD + hd] = f2bf(acc[i][j][r]);
        }
  }
}

// Output projection: ao_bf16 [8192,1024] @ Wo -> fp32 out. grid (8,64)
__global__ __launch_bounds__(256) void gemm_out_kernel(
    const unsigned short* __restrict__ ao, const unsigned short* __restrict__ woT,
    float* __restrict__ out) {
  __shared__ unsigned short lA[128 * 64];
  __shared__ unsigned short lB[128 * 64];
  int lane = threadIdx.x & 63, wave = threadIdx.x >> 6;
  int lr = lane & 15, quad = lane >> 4;
  int m0 = blockIdx.y * 128, n0 = blockIdx.x * 128;
  int m_base = m0 + (wave >> 1) * 64;
  int n_base = n0 + (wave & 1) * 64;
  float4_t z = {0.f, 0.f, 0.f, 0.f};
  float4_t acc[4][4];
#pragma unroll
  for (int i = 0; i < 4; ++i)
#pragma unroll
    for (int j = 0; j < 4; ++j) acc[i][j] = z;
  gemm_mainloop(ao, woT, m0, n0, lA, lB, acc);
#pragma unroll
  for (int i = 0; i < 4; ++i)
#pragma unroll
    for (int j = 0; j < 4; ++j)
#pragma unroll
      for (int r = 0; r < 4; ++r) {
        int m = m_base + i * 16 + quad * 4 + r;
        int n = n_base + j * 16 + lr;
        out[(size_t)m * Dm + n] = acc[i][j][r];
      }
}

// Flash attention (R2, verified). grid (16, B*H), block 256 (4 waves).
__global__ __launch_bounds__(256) void attn_kernel(
    const unsigned short* __restrict__ qbuf, const unsigned short* __restrict__ kbuf,
    const unsigned short* __restrict__ vtbuf, unsigned short* __restrict__ ao) {
  __shared__ unsigned short lk[64 * LDSPITCH];
  __shared__ unsigned short lv[64 * LDSPITCH];
  int bh = blockIdx.y;
  int wave = threadIdx.x >> 6, lane = threadIdx.x & 63;
  int lcol = lane & 15, quad = lane >> 4;
  const unsigned short* Q = qbuf + (size_t)bh * Sq * HD;
  const unsigned short* K = kbuf + (size_t)bh * Sq * HD;
  const unsigned short* Vt = vtbuf + (size_t)bh * HD * Sq;
  int b = bh >> 4, h = bh & 15;
  int srow = threadIdx.x >> 2;
  int scol = (threadIdx.x & 3) * 16;
  float4_t z = {0.f, 0.f, 0.f, 0.f};

  for (int half = 0; half < 2; ++half) {
    int ti = half == 0 ? (int)blockIdx.x : 31 - (int)blockIdx.x;
    int q0w = ti * 64 + wave * 16;
    int q_global = q0w + lcol;
    short8_t qf0 = *(const short8_t*)(Q + (size_t)(q0w + lcol) * HD + quad * 8);
    short8_t qf1 = *(const short8_t*)(Q + (size_t)(q0w + lcol) * HD + 32 + quad * 8);
    float m_i = -INFINITY, l_i = 0.f;
    float4_t o[4];
#pragma unroll
    for (int f = 0; f < 4; ++f) o[f] = z;

    int nkt = ti + 1;
    for (int kt = 0; kt < nkt; ++kt) {
      int key0 = kt * 64;
      __syncthreads();
      {
        const unsigned short* kg = K + (size_t)(key0 + srow) * HD + scol;
        const unsigned short* vg = Vt + (size_t)srow * Sq + key0 + scol;
        unsigned short* kl = lk + srow * LDSPITCH + scol;
        unsigned short* vl = lv + srow * LDSPITCH + scol;
        *(short8_t*)(kl) = *(const short8_t*)(kg);
        *(short8_t*)(kl + 8) = *(const short8_t*)(kg + 8);
        *(short8_t*)(vl) = *(const short8_t*)(vg);
        *(short8_t*)(vl + 8) = *(const short8_t*)(vg + 8);
      }
      __syncthreads();

      bool need_mask = (key0 + 63 > q0w);
      float s[16];
      float tmax = -INFINITY;
#pragma unroll
      for (int s4 = 0; s4 < 4; ++s4) {
        short8_t kf0 = *(const short8_t*)(lk + (s4 * 16 + lcol) * LDSPITCH + quad * 8);
        short8_t kf1 = *(const short8_t*)(lk + (s4 * 16 + lcol) * LDSPITCH + 32 + quad * 8);
        float4_t st = z;
        st = __builtin_amdgcn_mfma_f32_16x16x32_bf16(kf0, qf0, st, 0, 0, 0);
        st = __builtin_amdgcn_mfma_f32_16x16x32_bf16(kf1, qf1, st, 0, 0, 0);
#pragma unroll
        for (int r = 0; r < 4; ++r) {
          float v = st[r] * 0.125f;
          if (need_mask && (key0 + s4 * 16 + quad * 4 + r > q_global)) v = -INFINITY;
          s[s4 * 4 + r] = v;
          tmax = fmaxf(tmax, v);
        }
      }
      tmax = fmaxf(tmax, __shfl_xor(tmax, 16, 64));
      tmax = fmaxf(tmax, __shfl_xor(tmax, 32, 64));
      float m_new = fmaxf(m_i, tmax);
      float alpha = __expf(m_i - m_new);
      float psum = 0.f;
      short4_t pf[4];
#pragma unroll
      for (int s4 = 0; s4 < 4; ++s4)
#pragma unroll
        for (int r = 0; r < 4; ++r) {
          float p = __expf(s[s4 * 4 + r] - m_new);
          psum += p;
          pf[s4][r] = (short)f2bf(p);
        }
      psum += __shfl_xor(psum, 16, 64);
      psum += __shfl_xor(psum, 32, 64);
      l_i = l_i * alpha + psum;
      m_i = m_new;
      float at[4];
#pragma unroll
      for (int r = 0; r < 4; ++r) at[r] = __shfl(alpha, quad * 4 + r, 64);
#pragma unroll
      for (int f = 0; f < 4; ++f)
#pragma unroll
        for (int r = 0; r < 4; ++r) o[f][r] *= at[r];
#pragma unroll
      for (int f = 0; f < 4; ++f)
#pragma unroll
        for (int s4 = 0; s4 < 4; ++s4) {
          short4_t vf =
              *(const short4_t*)(lv + (f * 16 + lcol) * LDSPITCH + s4 * 16 + quad * 4);
          o[f] = __builtin_amdgcn_mfma_f32_16x16x16bf16_1k(pf[s4], vf, o[f], 0, 0, 0);
        }
    }

    float lt[4];
#pragma unroll
    for (int r = 0; r < 4; ++r) lt[r] = 1.f / __shfl(l_i, quad * 4 + r, 64);
#pragma unroll
    for (int f = 0; f < 4; ++f)
#pragma unroll
      for (int r = 0; r < 4; ++r) {
        int q = q0w + quad * 4 + r;
        int hd = f * 16 + lcol;
        ao[((size_t)b * Sq + q) * (NH * HD) + h * HD + hd] = f2bf(o[f][r] * lt[r]);
      }
  }
}

extern "C" void kernel_launch(void* const* d_in, const int* in_sizes, int n_in,
                              void* d_out, int out_size, void* d_ws, size_t ws_size,
                              hipStream_t stream) {
  const float* x = (const float*)d_in[0];
  const float* Wq = (const float*)d_in[1];
  const float* Wk = (const float*)d_in[2];
  const float* Wv = (const float*)d_in[3];
  const float* Wo = (const float*)d_in[4];
  float* out = (float*)d_out;

  char* ws = (char*)d_ws;
  size_t off = 0;
  auto carve = [&](size_t bytes) {
    void* p = ws + off;
    off += (bytes + 255) & ~(size_t)255;
    return p;
  };
  const size_t xe = (size_t)Bz * Sq * Dm;
  const size_t we = (size_t)Dm * Dm;
  unsigned short* xb = (unsigned short*)carve(xe * 2);
  unsigned short* wqT = (unsigned short*)carve(we * 2);
  unsigned short* wkT = (unsigned short*)carve(we * 2);
  unsigned short* wvT = (unsigned short*)carve(we * 2);
  unsigned short* woT = (unsigned short*)carve(we * 2);
  unsigned short* qb = (unsigned short*)carve(xe * 2);
  unsigned short* kb = (unsigned short*)carve(xe * 2);
  unsigned short* vt = (unsigned short*)carve(xe * 2);
  unsigned short* ao = (unsigned short*)carve(xe * 2);
  (void)ws_size;

  cast_x_kernel<<<xe / 4 / 256, 256, 0, stream>>>(x, xb);
  transpose_w_kernel<<<dim3(16, 16), 256, 0, stream>>>(Wq, wqT);
  transpose_w_kernel<<<dim3(16, 16), 256, 0, stream>>>(Wk, wkT);
  transpose_w_kernel<<<dim3(16, 16), 256, 0, stream>>>(Wv, wvT);
  transpose_w_kernel<<<dim3(16, 16), 256, 0, stream>>>(Wo, woT);
  gemm_qkv_kernel<<<dim3(8, 64, 3), 256, 0, stream>>>(xb, wqT, wkT, wvT, qb, kb, vt);
  attn_kernel<<<dim3(16, Bz * NH), 256, 0, stream>>>(qb, kb, vt, ao);
  gemm_out_kernel<<<dim3(8, 64), 256, 0, stream>>>(ao, woT, out);
}